// Round 12
// baseline (238.710 us; speedup 1.0000x reference)
//
#include <hip/hip_runtime.h>
#include <math.h>

#define N 4096
#define DQ 128
#define DIN 64
#define DC 32
#define NT 9          // full B panel: 9 n-tiles (128 v cols + z tile)
#define PST9 144
#define NIT 256       // N/16 i-tiles
#define KB2 8         // grid k-splits for main GEMM

typedef __attribute__((ext_vector_type(8))) short short8;
typedef __attribute__((ext_vector_type(8))) _Float16 half8;
typedef __attribute__((ext_vector_type(4))) float f32x4;

__device__ __forceinline__ unsigned short f2h(float x) {
  return __builtin_bit_cast(unsigned short, (_Float16)x);
}
__device__ __forceinline__ void async16(unsigned short* lds, const unsigned short* g) {
  __builtin_amdgcn_global_load_lds(
      (const __attribute__((address_space(1))) void*)g,
      (__attribute__((address_space(3))) void*)lds, 16, 0, 0);
}

// ---- shared epilogue: p*(h@W_av+b_av) -> single f16 into LDS tile -----------
__device__ __forceinline__ void v_phase(const float* hs_row, float p,
    const float* __restrict__ W_av_k, const float* __restrict__ b_av_k,
    int r, int d4, unsigned short* shh) {
  float a[4] = {b_av_k[d4], b_av_k[d4 + 1], b_av_k[d4 + 2], b_av_k[d4 + 3]};
  for (int c = 0; c < DQ; ++c) {
    const float hv = hs_row[c];
    const float4 w = *(const float4*)&W_av_k[c * DQ + d4];
    a[0] += hv * w.x; a[1] += hv * w.y; a[2] += hv * w.z; a[3] += hv * w.w;
  }
  const int nt = d4 >> 4;
#pragma unroll
  for (int e = 0; e < 4; ++e)
    shh[nt * 128 + ((d4 + e) & 15) * 8 + r] = f2h(p * a[e]);
  const int c32 = d4 >> 2;
  if (c32 < 16)
    shh[8 * 128 + c32 * 8 + r] = (c32 == 0) ? f2h(p) : 0;
}

__device__ __forceinline__ void v_store(int tid, int blk,
    const unsigned short* shh, unsigned short* __restrict__ Vf) {
  const int kt = blk >> 2, quad = blk & 3;
  if (tid < NT * 16) {
    const int nt = tid >> 4, l15 = tid & 15;
    const size_t dst = (((size_t)kt * NT + nt) * 64 + quad * 16 + l15) * 8;
    *(short8*)(Vf + dst) = *(const short8*)&shh[nt * 128 + l15 * 8];
  }
}

// ---- fused: blocks <8192 do exp-transpose units; blocks >=8192 do encode+V' --
__global__ __launch_bounds__(256) void kExpVS0(const float* __restrict__ trans,
    unsigned short* __restrict__ Ef,
    const float* __restrict__ x, const float* __restrict__ comms,
    const float* __restrict__ W_enc, const float* __restrict__ b_enc,
    const float* __restrict__ W_ad_k, const float* __restrict__ wa,
    const float* __restrict__ W_av_k, const float* __restrict__ b_av_k,
    unsigned short* __restrict__ Vf) {
  __shared__ __align__(16) char smem[10048];
  const int tid = threadIdx.x;
  const int bx = blockIdx.x;
  if (bx < 8192) {
    // ---- exp + f16 + frag-transpose of one 32x64 tile ----
    float* sh = (float*)smem;                 // 32 x 65
    const int ig = bx & 63;
    const int kt = bx >> 6;
    const int r = tid >> 3;
    const int c8 = (tid & 7) * 8;
    const float* src = &trans[((size_t)kt * 32 + r) * N + ig * 64 + c8];
    const float4 v0 = *(const float4*)src;
    const float4 v1 = *(const float4*)(src + 4);
    float* d = &sh[r * 65 + c8];
    d[0] = __expf(v0.x); d[1] = __expf(v0.y); d[2] = __expf(v0.z); d[3] = __expf(v0.w);
    d[4] = __expf(v1.x); d[5] = __expf(v1.y); d[6] = __expf(v1.z); d[7] = __expf(v1.w);
    __syncthreads();
    const int itl = tid >> 6;
    const int lane = tid & 63;
    const int quad = lane >> 4, l15 = lane & 15;
    const int col = itl * 16 + l15;
    unsigned short hb[8];
#pragma unroll
    for (int jj = 0; jj < 8; ++jj) hb[jj] = f2h(sh[(quad * 8 + jj) * 65 + col]);
    const short8 s = {(short)hb[0], (short)hb[1], (short)hb[2], (short)hb[3],
                      (short)hb[4], (short)hb[5], (short)hb[6], (short)hb[7]};
    *(short8*)(Ef + (((size_t)kt * NIT + ig * 4 + itl) * 64 + lane) * 8) = s;
  } else {
    // ---- encode + sa + p + V' for 8 rows ----
    const int blk = bx - 8192;
    float* xs = (float*)smem;                         // 8 x 96
    float* hs = (float*)(smem + 3072);                // 8 x 128
    float* u  = (float*)(smem + 7168);                // 128
    float* pb = (float*)(smem + 7680);                // 8
    unsigned short* shh = (unsigned short*)(smem + 7712);  // NT*128
    if (tid < 128) {
      const float4 v = *(const float4*)&x[(size_t)blk * 8 * DIN + tid * 4];
      const int idx = tid * 4, r = idx >> 6, c = idx & 63;
      xs[r * 96 + c] = v.x; xs[r * 96 + c + 1] = v.y;
      xs[r * 96 + c + 2] = v.z; xs[r * 96 + c + 3] = v.w;
    } else if (tid < 192) {
      const int t = tid - 128;
      const float4 v = *(const float4*)&comms[(size_t)blk * 8 * DC + t * 4];
      const int idx = t * 4, r = idx >> 5, c = idx & 31;
      xs[r * 96 + 64 + c] = v.x; xs[r * 96 + 64 + c + 1] = v.y;
      xs[r * 96 + 64 + c + 2] = v.z; xs[r * 96 + 64 + c + 3] = v.w;
    }
    if (tid < DQ) {
      float s = 0.f;
      const float* wrow = &W_ad_k[tid * DQ];
      for (int q = 0; q < DQ; ++q) s += wrow[q] * wa[q];
      u[tid] = s;
    }
    __syncthreads();
    const int r = tid >> 5;
    const int c32 = tid & 31;
    const int d4 = c32 * 4;
    {
      float a0 = b_enc[d4], a1 = b_enc[d4 + 1], a2 = b_enc[d4 + 2], a3 = b_enc[d4 + 3];
      for (int c = 0; c < 96; ++c) {
        const float hv = xs[r * 96 + c];
        const float4 w = *(const float4*)&W_enc[c * DQ + d4];
        a0 += hv * w.x; a1 += hv * w.y; a2 += hv * w.z; a3 += hv * w.w;
      }
      hs[r * DQ + d4] = a0; hs[r * DQ + d4 + 1] = a1;
      hs[r * DQ + d4 + 2] = a2; hs[r * DQ + d4 + 3] = a3;
    }
    __syncthreads();
    float part = 0.f;
    for (int c = c32; c < DQ; c += 32) part += hs[r * DQ + c] * u[c];
#pragma unroll
    for (int m = 16; m > 0; m >>= 1) part += __shfl_xor(part, m, 32);
    if (c32 == 0) pb[r] = __expf(part);
    __syncthreads();
    v_phase(&hs[r * DQ], pb[r], W_av_k, b_av_k, r, d4, shh);
    __syncthreads();
    v_store(tid, blk, shh, Vf);
  }
}

// ---- rounds 1,2: P-reduce -> h + sa + p + V' (full panel) ----
__global__ __launch_bounds__(256) void kVSR(const float* __restrict__ P,
    const float* __restrict__ W_ad_k, const float* __restrict__ wa,
    const float* __restrict__ W_av_k, const float* __restrict__ b_av_k,
    unsigned short* __restrict__ Vf) {
  __shared__ float hs[8][DQ];
  __shared__ float u[DQ];
  __shared__ float pb[8];
  __shared__ __align__(16) unsigned short shh[NT * 128];
  const int tid = threadIdx.x;
  const int r = tid >> 5;
  const int c32 = tid & 31;
  const int d4 = c32 * 4;
  const int j = blockIdx.x * 8 + r;
  if (tid < DQ) {
    float s = 0.f;
    const float* wrow = &W_ad_k[tid * DQ];
    for (int q = 0; q < DQ; ++q) s += wrow[q] * wa[q];
    u[tid] = s;
  }
  float4 num = {0.f, 0.f, 0.f, 0.f};
  float den = 0.f;
#pragma unroll
  for (int s = 0; s < KB2; ++s) {
    const float* b = &P[((size_t)s * N + j) * PST9];
    const float4 v = *(const float4*)&b[d4];
    num.x += v.x; num.y += v.y; num.z += v.z; num.w += v.w;
    den += b[128];
  }
  const float inv = 1.f / den;
  hs[r][d4] = num.x * inv; hs[r][d4 + 1] = num.y * inv;
  hs[r][d4 + 2] = num.z * inv; hs[r][d4 + 3] = num.w * inv;
  __syncthreads();
  float part = 0.f;
  for (int c = c32; c < DQ; c += 32) part += hs[r][c] * u[c];
#pragma unroll
  for (int m = 16; m > 0; m >>= 1) part += __shfl_xor(part, m, 32);
  if (c32 == 0) pb[r] = __expf(part);
  __syncthreads();
  v_phase(hs[r], pb[r], W_av_k, b_av_k, r, d4, shh);
  __syncthreads();
  v_store(tid, blockIdx.x, shh, Vf);
}

// ---- round 2: P-reduce -> h + sa + p + CONTRACTED V' (v.W_dec, p) ----
__global__ __launch_bounds__(256) void kVSRc(const float* __restrict__ P,
    const float* __restrict__ W_ad_k, const float* __restrict__ wa,
    const float* __restrict__ W_av_k, const float* __restrict__ b_av_k,
    const float* __restrict__ W_dec, unsigned short* __restrict__ Vc) {
  __shared__ float hs[8][DQ];
  __shared__ float u[DQ];
  __shared__ float pb[8];
  const int tid = threadIdx.x;
  const int r = tid >> 5;
  const int c32 = tid & 31;
  const int d4 = c32 * 4;
  const int j = blockIdx.x * 8 + r;
  if (tid < DQ) {
    float s = 0.f;
    const float* wrow = &W_ad_k[tid * DQ];
    for (int q = 0; q < DQ; ++q) s += wrow[q] * wa[q];
    u[tid] = s;
  }
  float4 num = {0.f, 0.f, 0.f, 0.f};
  float den = 0.f;
#pragma unroll
  for (int s = 0; s < KB2; ++s) {
    const float* b = &P[((size_t)s * N + j) * PST9];
    const float4 v = *(const float4*)&b[d4];
    num.x += v.x; num.y += v.y; num.z += v.z; num.w += v.w;
    den += b[128];
  }
  const float inv = 1.f / den;
  hs[r][d4] = num.x * inv; hs[r][d4 + 1] = num.y * inv;
  hs[r][d4 + 2] = num.z * inv; hs[r][d4 + 3] = num.w * inv;
  __syncthreads();
  float part = 0.f;
  for (int c = c32; c < DQ; c += 32) part += hs[r][c] * u[c];
#pragma unroll
  for (int m = 16; m > 0; m >>= 1) part += __shfl_xor(part, m, 32);
  if (c32 == 0) pb[r] = __expf(part);
  __syncthreads();
  float a[4] = {b_av_k[d4], b_av_k[d4 + 1], b_av_k[d4 + 2], b_av_k[d4 + 3]};
  for (int c = 0; c < DQ; ++c) {
    const float hv = hs[r][c];
    const float4 w = *(const float4*)&W_av_k[c * DQ + d4];
    a[0] += hv * w.x; a[1] += hv * w.y; a[2] += hv * w.z; a[3] += hv * w.w;
  }
  float vd = a[0] * W_dec[d4] + a[1] * W_dec[d4 + 1]
           + a[2] * W_dec[d4 + 2] + a[3] * W_dec[d4 + 3];
#pragma unroll
  for (int m = 16; m > 0; m >>= 1) vd += __shfl_xor(vd, m, 32);
  const float p = pb[r];
  if (c32 < 16) {
    const int blk = blockIdx.x;
    const size_t ix = (((size_t)(blk >> 2)) * 64 + (blk & 3) * 16 + c32) * 8 + r;
    Vc[ix] = (c32 == 0) ? f2h(p * vd) : (c32 == 1) ? f2h(p) : 0;
  }
}

// ---- main MFMA GEMM: 4 i-tiles/wave, waves split k 4-ways, KB2 grid splits --
// Per wave per k-step: stage 9KB B panel (wave-private LDS dbuf, manual vmcnt),
// 4 A-frag loads, 36 MFMAs. Epilogue: two-pass LDS reduce over 4 waves.
__global__ __launch_bounds__(256, 2) void kGemm9(
    const unsigned short* __restrict__ Ef, const unsigned short* __restrict__ Vf,
    float* __restrict__ P) {
  __shared__ __align__(16) unsigned short lds[4][2][NT * 512];  // 73728 B
  const int tid = threadIdx.x;
  const int w = tid >> 6, lane = tid & 63;
  const int quad = lane >> 4, l15 = lane & 15;
  const int it0 = blockIdx.x * 4;
  const size_t ktw = (size_t)blockIdx.y * 16 + w * 4;   // wave's 4 k-steps

  f32x4 acc[4][NT];
#pragma unroll
  for (int ti = 0; ti < 4; ++ti)
#pragma unroll
    for (int nt = 0; nt < NT; ++nt) acc[ti][nt] = (f32x4){0.f, 0.f, 0.f, 0.f};

#pragma unroll
  for (int c = 0; c < NT; ++c)
    async16(&lds[w][0][c * 512], Vf + (ktw * NT + c) * 512 + lane * 8);
  half8 A0[4], A1[4];
#pragma unroll
  for (int ti = 0; ti < 4; ++ti)
    A0[ti] = __builtin_bit_cast(half8,
        *(const short8*)(Ef + ((ktw * NIT + it0 + ti) * 64 + lane) * 8));

#pragma unroll
  for (int t = 0; t < 4; ++t) {
    if (t < 3) {
      const size_t ktn = ktw + t + 1;
#pragma unroll
      for (int c = 0; c < NT; ++c)
        async16(&lds[w][(t + 1) & 1][c * 512], Vf + (ktn * NT + c) * 512 + lane * 8);
#pragma unroll
      for (int ti = 0; ti < 4; ++ti)
        A1[ti] = __builtin_bit_cast(half8,
            *(const short8*)(Ef + ((ktn * NIT + it0 + ti) * 64 + lane) * 8));
      __builtin_amdgcn_s_waitcnt(0xF70 | (NT + 4));  // keep t+1's 13 in flight
    } else {
      __builtin_amdgcn_s_waitcnt(0xF70);             // vmcnt(0)
    }
    const unsigned short* bb = lds[w][t & 1];
#pragma unroll
    for (int nt = 0; nt < NT; ++nt) {
      const half8 Bh = __builtin_bit_cast(half8,
          *(const short8*)(bb + nt * 512 + lane * 8));
#pragma unroll
      for (int ti = 0; ti < 4; ++ti)
        acc[ti][nt] = __builtin_amdgcn_mfma_f32_16x16x32_f16(A0[ti], Bh, acc[ti][nt], 0, 0, 0);
    }
    if (t < 3) {
#pragma unroll
      for (int ti = 0; ti < 4; ++ti) A0[ti] = A1[ti];
    }
  }
  // ---- two-pass reduce over waves (147KB of acc > 73.7KB LDS) ----
  float* lf = (float*)lds;
  float* Pb = P + (size_t)blockIdx.y * N * PST9;
#pragma unroll
  for (int half = 0; half < 2; ++half) {
    __syncthreads();
#pragma unroll
    for (int ti2 = 0; ti2 < 2; ++ti2)
#pragma unroll
      for (int nt = 0; nt < NT; ++nt) {
        const f32x4 a = acc[half * 2 + ti2][nt];
        float4 v; v.x = a[0]; v.y = a[1]; v.z = a[2]; v.w = a[3];
        *(float4*)&lf[((w * 2 + ti2) * NT + nt) * 256 + lane * 4] = v;
      }
    __syncthreads();
    for (int p = w; p < 2 * NT; p += 4) {
      const int ti2 = p / NT, nt = p % NT;
      float4 s = {0.f, 0.f, 0.f, 0.f};
#pragma unroll
      for (int wv = 0; wv < 4; ++wv) {
        const float4 v = *(const float4*)&lf[((wv * 2 + ti2) * NT + nt) * 256 + lane * 4];
        s.x += v.x; s.y += v.y; s.z += v.z; s.w += v.w;
      }
      if (nt != 8 || l15 == 0) {
        const float sr[4] = {s.x, s.y, s.z, s.w};
#pragma unroll
        for (int r = 0; r < 4; ++r) {
          const int i = (it0 + half * 2 + ti2) * 16 + quad * 4 + r;
          Pb[(size_t)i * PST9 + nt * 16 + l15] = sr[r];
        }
      }
    }
  }
}

// ---- contracted GEMM + out: 1 i-tile/block, 8 waves split 128 k-steps -------
__global__ __launch_bounds__(512) void kGemmC(
    const unsigned short* __restrict__ Ef, const unsigned short* __restrict__ Vc,
    const float* __restrict__ b_dec, const int* __restrict__ mask,
    float* __restrict__ out) {
  __shared__ __align__(16) unsigned short lds[8][2][512];
  __shared__ float rf[8][256];
  __shared__ float nd[2][16];
  const int tid = threadIdx.x;
  const int w = tid >> 6, lane = tid & 63;
  const int quad = lane >> 4, l15 = lane & 15;
  const int it = blockIdx.x;
  const size_t ktw = (size_t)w * 16;                   // wave's 16 k-steps

  f32x4 acc = {0.f, 0.f, 0.f, 0.f};
  async16(&lds[w][0][0], Vc + ktw * 512 + lane * 8);
  half8 A0 = __builtin_bit_cast(half8,
      *(const short8*)(Ef + ((ktw * NIT + it) * 64 + lane) * 8));
  half8 A1;
#pragma unroll
  for (int t = 0; t < 16; ++t) {
    if (t < 15) {
      const size_t ktn = ktw + t + 1;
      async16(&lds[w][(t + 1) & 1][0], Vc + ktn * 512 + lane * 8);
      A1 = __builtin_bit_cast(half8,
          *(const short8*)(Ef + ((ktn * NIT + it) * 64 + lane) * 8));
      __builtin_amdgcn_s_waitcnt(0xF72);               // vmcnt(2)
    } else {
      __builtin_amdgcn_s_waitcnt(0xF70);               // vmcnt(0)
    }
    const half8 Bh = __builtin_bit_cast(half8,
        *(const short8*)(&lds[w][t & 1][0] + lane * 8));
    acc = __builtin_amdgcn_mfma_f32_16x16x32_f16(A0, Bh, acc, 0, 0, 0);
    if (t < 15) A0 = A1;
  }
  float4 v; v.x = acc[0]; v.y = acc[1]; v.z = acc[2]; v.w = acc[3];
  *(float4*)&rf[w][lane * 4] = v;
  __syncthreads();
  if (tid < 64) {
    float s[4];
#pragma unroll
    for (int r = 0; r < 4; ++r) {
      float t = 0.f;
#pragma unroll
      for (int wv = 0; wv < 8; ++wv) t += rf[wv][tid * 4 + r];
      s[r] = t;
    }
    if (l15 < 2) {
#pragma unroll
      for (int r = 0; r < 4; ++r) nd[l15][quad * 4 + r] = s[r];
    }
  }
  __syncthreads();
  if (tid < 16) {
    const int i = it * 16 + tid;
    out[i] = (mask[i] == 0) ? -INFINITY : nd[0][tid] / nd[1][tid] + b_dec[0];
  }
}

extern "C" void kernel_launch(void* const* d_in, const int* in_sizes, int n_in,
                              void* d_out, int out_size, void* d_ws, size_t ws_size,
                              hipStream_t stream) {
  (void)in_sizes; (void)n_in; (void)out_size; (void)ws_size;
  const float* x     = (const float*)d_in[0];
  const float* comms = (const float*)d_in[1];
  const float* trans = (const float*)d_in[2];
  const int*   mask  = (const int*)d_in[3];
  const float* W_enc = (const float*)d_in[4];
  const float* b_enc = (const float*)d_in[5];
  const float* W_ad  = (const float*)d_in[6];
  // d_in[7]=b_ad, d_in[9]=b_att cancel inside the row softmax
  const float* w_att = (const float*)d_in[8];
  const float* W_av  = (const float*)d_in[10];
  const float* b_av  = (const float*)d_in[11];
  const float* W_dec = (const float*)d_in[12];
  const float* b_dec = (const float*)d_in[13];
  float* out         = (float*)d_out;

  char* ws = (char*)d_ws;
  unsigned short* Vf = (unsigned short*)ws;  ws += (size_t)(N / 32) * NT * 512 * 2;
  unsigned short* Vc = (unsigned short*)ws;  ws += (size_t)(N / 32) * 512 * 2;
  unsigned short* Ef = (unsigned short*)ws;  ws += (size_t)N * N * 2;
  float* P  = (float*)ws;

  kExpVS0<<<8192 + 512, 256, 0, stream>>>(trans, Ef, x, comms, W_enc, b_enc,
                                          W_ad, w_att, W_av, b_av, Vf);
  kGemm9<<<dim3(NIT / 4, KB2), 256, 0, stream>>>(Ef, Vf, P);

  kVSR<<<N / 8, 256, 0, stream>>>(P, W_ad + (size_t)1 * DQ * DQ,
                                  w_att + 2 * DQ, W_av + (size_t)1 * DQ * DQ,
                                  b_av + DQ, Vf);
  kGemm9<<<dim3(NIT / 4, KB2), 256, 0, stream>>>(Ef, Vf, P);

  kVSRc<<<N / 8, 256, 0, stream>>>(P, W_ad + (size_t)2 * DQ * DQ,
                                   w_att + 4 * DQ, W_av + (size_t)2 * DQ * DQ,
                                   b_av + 2 * DQ, W_dec, Vc);
  kGemmC<<<NIT, 512, 0, stream>>>(Ef, Vc, b_dec, mask, out);
}

// Round 13
// 215.850 us; speedup vs baseline: 1.1059x; 1.1059x over previous
//
#include <hip/hip_runtime.h>
#include <math.h>

#define N 4096
#define DQ 128
#define DIN 64
#define DC 32
#define NT 9          // full B panel: 9 n-tiles (128 v cols + z tile)
#define PST9 144
#define PST1 16
#define NIT 256       // N/16 i-tiles
#define KB 4          // grid k-splits
#define SW 8          // k-steps per wave: N / KB / 32 rows / 4 waves
#define ET 4          // k-tiles per kExp block

typedef __attribute__((ext_vector_type(8))) short short8;
typedef __attribute__((ext_vector_type(8))) _Float16 half8;
typedef __attribute__((ext_vector_type(4))) float f32x4;

__device__ __forceinline__ unsigned short f2h(float x) {
  return __builtin_bit_cast(unsigned short, (_Float16)x);
}
__device__ __forceinline__ void async16(unsigned short* lds, const unsigned short* g) {
  __builtin_amdgcn_global_load_lds(
      (const __attribute__((address_space(1))) void*)g,
      (__attribute__((address_space(3))) void*)lds, 16, 0, 0);
}

// ---- kExp: Ef = f16(exp(trans)) in MFMA A-frag layout -----------------------
// 4 k-tiles per block, LDS double-buffered, 1 barrier/tile; global loads for
// tile t+1 stay in flight across tile t's transpose.
__global__ __launch_bounds__(256) void kExp(const float* __restrict__ trans,
                                            unsigned short* __restrict__ Ef) {
  __shared__ float sh[2][32 * 65];
  const int tid = threadIdx.x;
  const int ig = blockIdx.x;        // i-group of 64 (0..63)
  const int ktg = blockIdx.y;       // group of ET k-tiles (0..31)
  const int r = tid >> 3;           // j within tile (0..31)
  const int c8 = (tid & 7) * 8;     // i within group
  const int itl = tid >> 6;         // i-tile within group (0..3)
  const int lane = tid & 63;
  const int quad = lane >> 4, l15 = lane & 15;
  const int col = itl * 16 + l15;

  float4 v0, v1;
  {
    const float* src = &trans[((size_t)ktg * ET * 32 + r) * N + ig * 64 + c8];
    v0 = *(const float4*)src;
    v1 = *(const float4*)(src + 4);
  }
#pragma unroll
  for (int t = 0; t < ET; ++t) {
    const int kt = ktg * ET + t;
    float* d = &sh[t & 1][r * 65 + c8];
    d[0] = __expf(v0.x); d[1] = __expf(v0.y); d[2] = __expf(v0.z); d[3] = __expf(v0.w);
    d[4] = __expf(v1.x); d[5] = __expf(v1.y); d[6] = __expf(v1.z); d[7] = __expf(v1.w);
    if (t + 1 < ET) {   // prefetch next tile; consumed after the barrier
      const float* src = &trans[((size_t)(kt + 1) * 32 + r) * N + ig * 64 + c8];
      v0 = *(const float4*)src;
      v1 = *(const float4*)(src + 4);
    }
    __syncthreads();
    unsigned short hb[8];
#pragma unroll
    for (int jj = 0; jj < 8; ++jj)
      hb[jj] = f2h(sh[t & 1][(quad * 8 + jj) * 65 + col]);
    const short8 s = {(short)hb[0], (short)hb[1], (short)hb[2], (short)hb[3],
                      (short)hb[4], (short)hb[5], (short)hb[6], (short)hb[7]};
    *(short8*)(Ef + (((size_t)kt * NIT + ig * 4 + itl) * 64 + lane) * 8) = s;
  }
}

// ---- shared epilogue: p*(h@W_av+b_av) -> single f16 into LDS tile -----------
__device__ __forceinline__ void v_phase(const float* hs_row, float p,
    const float* __restrict__ W_av_k, const float* __restrict__ b_av_k,
    int r, int d4, unsigned short* shh) {
  float a[4] = {b_av_k[d4], b_av_k[d4 + 1], b_av_k[d4 + 2], b_av_k[d4 + 3]};
  for (int c = 0; c < DQ; ++c) {
    const float hv = hs_row[c];
    const float4 w = *(const float4*)&W_av_k[c * DQ + d4];
    a[0] += hv * w.x; a[1] += hv * w.y; a[2] += hv * w.z; a[3] += hv * w.w;
  }
  const int nt = d4 >> 4;
#pragma unroll
  for (int e = 0; e < 4; ++e)
    shh[nt * 128 + ((d4 + e) & 15) * 8 + r] = f2h(p * a[e]);
  const int c32 = d4 >> 2;
  if (c32 < 16)
    shh[8 * 128 + c32 * 8 + r] = (c32 == 0) ? f2h(p) : 0;
}

__device__ __forceinline__ void v_store(int tid, int blk,
    const unsigned short* shh, unsigned short* __restrict__ Vf) {
  const int kt = blk >> 2, quad = blk & 3;
  if (tid < NT * 16) {
    const int nt = tid >> 4, l15 = tid & 15;
    const size_t dst = (((size_t)kt * NT + nt) * 64 + quad * 16 + l15) * 8;
    *(short8*)(Vf + dst) = *(const short8*)&shh[nt * 128 + l15 * 8];
  }
}

// ---- round 0: encode + sa + p + V' fused (8 rows per block) ----
__global__ __launch_bounds__(256) void kVS0(const float* __restrict__ x,
    const float* __restrict__ comms, const float* __restrict__ W_enc,
    const float* __restrict__ b_enc, const float* __restrict__ W_ad_k,
    const float* __restrict__ wa, const float* __restrict__ W_av_k,
    const float* __restrict__ b_av_k, unsigned short* __restrict__ Vf) {
  __shared__ float xs[8][96];
  __shared__ float hs[8][DQ];
  __shared__ float u[DQ];
  __shared__ float pb[8];
  __shared__ __align__(16) unsigned short shh[NT * 128];
  const int tid = threadIdx.x;
  const int blk = blockIdx.x;
  if (tid < 128) {
    const float4 v = *(const float4*)&x[(size_t)blk * 8 * DIN + tid * 4];
    const int idx = tid * 4, r = idx >> 6, c = idx & 63;
    xs[r][c] = v.x; xs[r][c + 1] = v.y; xs[r][c + 2] = v.z; xs[r][c + 3] = v.w;
  } else if (tid < 192) {
    const int t = tid - 128;
    const float4 v = *(const float4*)&comms[(size_t)blk * 8 * DC + t * 4];
    const int idx = t * 4, r = idx >> 5, c = idx & 31;
    xs[r][64 + c] = v.x; xs[r][64 + c + 1] = v.y; xs[r][64 + c + 2] = v.z; xs[r][64 + c + 3] = v.w;
  }
  if (tid < DQ) {
    float s = 0.f;
    const float* wrow = &W_ad_k[tid * DQ];
    for (int q = 0; q < DQ; ++q) s += wrow[q] * wa[q];
    u[tid] = s;
  }
  __syncthreads();
  const int r = tid >> 5;
  const int c32 = tid & 31;
  const int d4 = c32 * 4;
  {
    float a0 = b_enc[d4], a1 = b_enc[d4 + 1], a2 = b_enc[d4 + 2], a3 = b_enc[d4 + 3];
    for (int c = 0; c < 96; ++c) {
      const float hv = xs[r][c];
      const float4 w = *(const float4*)&W_enc[c * DQ + d4];
      a0 += hv * w.x; a1 += hv * w.y; a2 += hv * w.z; a3 += hv * w.w;
    }
    hs[r][d4] = a0; hs[r][d4 + 1] = a1; hs[r][d4 + 2] = a2; hs[r][d4 + 3] = a3;
  }
  __syncthreads();
  float part = 0.f;
  for (int c = c32; c < DQ; c += 32) part += hs[r][c] * u[c];
#pragma unroll
  for (int m = 16; m > 0; m >>= 1) part += __shfl_xor(part, m, 32);
  if (c32 == 0) pb[r] = __expf(part);
  __syncthreads();
  v_phase(hs[r], pb[r], W_av_k, b_av_k, r, d4, shh);
  __syncthreads();
  v_store(tid, blk, shh, Vf);
}

// ---- round 1: P-reduce -> h + sa + p + V' (full panel) ----
__global__ __launch_bounds__(256) void kVSR(const float* __restrict__ P,
    const float* __restrict__ W_ad_k, const float* __restrict__ wa,
    const float* __restrict__ W_av_k, const float* __restrict__ b_av_k,
    unsigned short* __restrict__ Vf) {
  __shared__ float hs[8][DQ];
  __shared__ float u[DQ];
  __shared__ float pb[8];
  __shared__ __align__(16) unsigned short shh[NT * 128];
  const int tid = threadIdx.x;
  const int r = tid >> 5;
  const int c32 = tid & 31;
  const int d4 = c32 * 4;
  const int j = blockIdx.x * 8 + r;
  if (tid < DQ) {
    float s = 0.f;
    const float* wrow = &W_ad_k[tid * DQ];
    for (int q = 0; q < DQ; ++q) s += wrow[q] * wa[q];
    u[tid] = s;
  }
  float4 num = {0.f, 0.f, 0.f, 0.f};
  float den = 0.f;
#pragma unroll
  for (int s = 0; s < KB; ++s) {
    const float* b = &P[((size_t)s * N + j) * PST9];
    const float4 v = *(const float4*)&b[d4];
    num.x += v.x; num.y += v.y; num.z += v.z; num.w += v.w;
    den += b[128];
  }
  const float inv = 1.f / den;
  hs[r][d4] = num.x * inv; hs[r][d4 + 1] = num.y * inv;
  hs[r][d4 + 2] = num.z * inv; hs[r][d4 + 3] = num.w * inv;
  __syncthreads();
  float part = 0.f;
  for (int c = c32; c < DQ; c += 32) part += hs[r][c] * u[c];
#pragma unroll
  for (int m = 16; m > 0; m >>= 1) part += __shfl_xor(part, m, 32);
  if (c32 == 0) pb[r] = __expf(part);
  __syncthreads();
  v_phase(hs[r], pb[r], W_av_k, b_av_k, r, d4, shh);
  __syncthreads();
  v_store(tid, blockIdx.x, shh, Vf);
}

// ---- round 2: P-reduce -> h + sa + p + CONTRACTED V' (v.W_dec, p) ----
__global__ __launch_bounds__(256) void kVSRc(const float* __restrict__ P,
    const float* __restrict__ W_ad_k, const float* __restrict__ wa,
    const float* __restrict__ W_av_k, const float* __restrict__ b_av_k,
    const float* __restrict__ W_dec, unsigned short* __restrict__ Vc) {
  __shared__ float hs[8][DQ];
  __shared__ float u[DQ];
  __shared__ float pb[8];
  const int tid = threadIdx.x;
  const int r = tid >> 5;
  const int c32 = tid & 31;
  const int d4 = c32 * 4;
  const int j = blockIdx.x * 8 + r;
  if (tid < DQ) {
    float s = 0.f;
    const float* wrow = &W_ad_k[tid * DQ];
    for (int q = 0; q < DQ; ++q) s += wrow[q] * wa[q];
    u[tid] = s;
  }
  float4 num = {0.f, 0.f, 0.f, 0.f};
  float den = 0.f;
#pragma unroll
  for (int s = 0; s < KB; ++s) {
    const float* b = &P[((size_t)s * N + j) * PST9];
    const float4 v = *(const float4*)&b[d4];
    num.x += v.x; num.y += v.y; num.z += v.z; num.w += v.w;
    den += b[128];
  }
  const float inv = 1.f / den;
  hs[r][d4] = num.x * inv; hs[r][d4 + 1] = num.y * inv;
  hs[r][d4 + 2] = num.z * inv; hs[r][d4 + 3] = num.w * inv;
  __syncthreads();
  float part = 0.f;
  for (int c = c32; c < DQ; c += 32) part += hs[r][c] * u[c];
#pragma unroll
  for (int m = 16; m > 0; m >>= 1) part += __shfl_xor(part, m, 32);
  if (c32 == 0) pb[r] = __expf(part);
  __syncthreads();
  float a[4] = {b_av_k[d4], b_av_k[d4 + 1], b_av_k[d4 + 2], b_av_k[d4 + 3]};
  for (int c = 0; c < DQ; ++c) {
    const float hv = hs[r][c];
    const float4 w = *(const float4*)&W_av_k[c * DQ + d4];
    a[0] += hv * w.x; a[1] += hv * w.y; a[2] += hv * w.z; a[3] += hv * w.w;
  }
  float vd = a[0] * W_dec[d4] + a[1] * W_dec[d4 + 1]
           + a[2] * W_dec[d4 + 2] + a[3] * W_dec[d4 + 3];
#pragma unroll
  for (int m = 16; m > 0; m >>= 1) vd += __shfl_xor(vd, m, 32);
  const float p = pb[r];
  if (c32 < 16) {
    const int blk = blockIdx.x;
    const size_t ix = (((size_t)(blk >> 2)) * 64 + (blk & 3) * 16 + c32) * 8 + r;
    Vc[ix] = (c32 == 0) ? f2h(p * vd) : (c32 == 1) ? f2h(p) : 0;
  }
}

// ---- MFMA GEMM, in-block k-split (R11 structure, measured good) -------------
template <int NTT, int PST>
__global__ __launch_bounds__(256) void kGemmR(
    const unsigned short* __restrict__ Ef, const unsigned short* __restrict__ Vf,
    float* __restrict__ P) {
  __shared__ __align__(16) unsigned short lds[4 * 2 * NTT * 512];
  const int tid = threadIdx.x;
  const int w = tid >> 6, lane = tid & 63;
  const int quad = lane >> 4, l15 = lane & 15;
  const int it0 = blockIdx.x * 2;
  const size_t ktw = (size_t)blockIdx.y * (4 * SW) + w * SW;
  unsigned short* myL = lds + w * (2 * NTT * 512);

  f32x4 acc[2][NTT];
#pragma unroll
  for (int ti = 0; ti < 2; ++ti)
#pragma unroll
    for (int nt = 0; nt < NTT; ++nt) acc[ti][nt] = (f32x4){0.f, 0.f, 0.f, 0.f};

#pragma unroll
  for (int c = 0; c < NTT; ++c)
    async16(myL + c * 512, Vf + (ktw * NTT + c) * 512 + lane * 8);
  half8 A0[2], A1[2];
#pragma unroll
  for (int ti = 0; ti < 2; ++ti)
    A0[ti] = __builtin_bit_cast(half8,
        *(const short8*)(Ef + ((ktw * NIT + it0 + ti) * 64 + lane) * 8));

#pragma unroll
  for (int t = 0; t < SW; ++t) {
    if (t + 1 < SW) {
      const size_t ktn = ktw + t + 1;
#pragma unroll
      for (int c = 0; c < NTT; ++c)
        async16(myL + ((t + 1) & 1) * NTT * 512 + c * 512,
                Vf + (ktn * NTT + c) * 512 + lane * 8);
#pragma unroll
      for (int ti = 0; ti < 2; ++ti)
        A1[ti] = __builtin_bit_cast(half8,
            *(const short8*)(Ef + ((ktn * NIT + it0 + ti) * 64 + lane) * 8));
      __builtin_amdgcn_s_waitcnt(0xF70 | (NTT + 2));
    } else {
      __builtin_amdgcn_s_waitcnt(0xF70);
    }
    const unsigned short* bb = myL + (t & 1) * NTT * 512;
#pragma unroll
    for (int nt = 0; nt < NTT; ++nt) {
      const half8 Bh = __builtin_bit_cast(half8,
          *(const short8*)(bb + nt * 512 + lane * 8));
      acc[0][nt] = __builtin_amdgcn_mfma_f32_16x16x32_f16(A0[0], Bh, acc[0][nt], 0, 0, 0);
      acc[1][nt] = __builtin_amdgcn_mfma_f32_16x16x32_f16(A0[1], Bh, acc[1][nt], 0, 0, 0);
    }
    if (t + 1 < SW) { A0[0] = A1[0]; A0[1] = A1[1]; }
  }
  __syncthreads();
  float* lf = (float*)lds;
#pragma unroll
  for (int ti = 0; ti < 2; ++ti)
#pragma unroll
    for (int nt = 0; nt < NTT; ++nt) {
      float4 v; v.x = acc[ti][nt][0]; v.y = acc[ti][nt][1];
      v.z = acc[ti][nt][2]; v.w = acc[ti][nt][3];
      *(float4*)&lf[(w * 2 * NTT + ti * NTT + nt) * 256 + lane * 4] = v;
    }
  __syncthreads();
  float* Pb = P + (size_t)blockIdx.y * N * PST;
  for (int p = w; p < 2 * NTT; p += 4) {
    const int ti = p / NTT, nt = p % NTT;
    float4 s = {0.f, 0.f, 0.f, 0.f};
#pragma unroll
    for (int wv = 0; wv < 4; ++wv) {
      const float4 v = *(const float4*)&lf[(wv * 2 * NTT + p) * 256 + lane * 4];
      s.x += v.x; s.y += v.y; s.z += v.z; s.w += v.w;
    }
    const float sr[4] = {s.x, s.y, s.z, s.w};
    if (NTT == 1 || nt != 8 || l15 == 0) {
#pragma unroll
      for (int r = 0; r < 4; ++r) {
        const int i = (it0 + ti) * 16 + quad * 4 + r;
        Pb[(size_t)i * PST + nt * 16 + l15] = sr[r];
      }
    }
  }
}

// ---- final: out[i] = numc/den + b_dec (P3 has 2 live cols) ----
__global__ __launch_bounds__(256) void kOut(const float* __restrict__ P3,
    const float* __restrict__ b_dec, const int* __restrict__ mask,
    float* __restrict__ out) {
  const int i = blockIdx.x * 256 + threadIdx.x;
  float num = 0.f, den = 0.f;
#pragma unroll
  for (int s = 0; s < KB; ++s) {
    const float* b = &P3[((size_t)s * N + i) * PST1];
    num += b[0];
    den += b[1];
  }
  out[i] = (mask[i] == 0) ? -INFINITY : num / den + b_dec[0];
}

extern "C" void kernel_launch(void* const* d_in, const int* in_sizes, int n_in,
                              void* d_out, int out_size, void* d_ws, size_t ws_size,
                              hipStream_t stream) {
  (void)in_sizes; (void)n_in; (void)out_size; (void)ws_size;
  const float* x     = (const float*)d_in[0];
  const float* comms = (const float*)d_in[1];
  const float* trans = (const float*)d_in[2];
  const int*   mask  = (const int*)d_in[3];
  const float* W_enc = (const float*)d_in[4];
  const float* b_enc = (const float*)d_in[5];
  const float* W_ad  = (const float*)d_in[6];
  // d_in[7]=b_ad, d_in[9]=b_att cancel inside the row softmax
  const float* w_att = (const float*)d_in[8];
  const float* W_av  = (const float*)d_in[10];
  const float* b_av  = (const float*)d_in[11];
  const float* W_dec = (const float*)d_in[12];
  const float* b_dec = (const float*)d_in[13];
  float* out         = (float*)d_out;

  char* ws = (char*)d_ws;
  unsigned short* Vf = (unsigned short*)ws;  ws += (size_t)(N / 32) * NT * 512 * 2;
  unsigned short* Vc = (unsigned short*)ws;  ws += (size_t)(N / 32) * 512 * 2;
  unsigned short* Ef = (unsigned short*)ws;  ws += (size_t)N * N * 2;
  float* P  = (float*)ws;                    ws += (size_t)KB * N * PST9 * 4;
  float* P3 = (float*)ws;

  kExp<<<dim3(64, 128 / ET), 256, 0, stream>>>(trans, Ef);
  kVS0<<<N / 8, 256, 0, stream>>>(x, comms, W_enc, b_enc, W_ad, w_att,
                                  W_av, b_av, Vf);
  kGemmR<NT, PST9><<<dim3(NIT / 2, KB), 256, 0, stream>>>(Ef, Vf, P);

  kVSR<<<N / 8, 256, 0, stream>>>(P, W_ad + (size_t)1 * DQ * DQ,
                                  w_att + 2 * DQ, W_av + (size_t)1 * DQ * DQ,
                                  b_av + DQ, Vf);
  kGemmR<NT, PST9><<<dim3(NIT / 2, KB), 256, 0, stream>>>(Ef, Vf, P);

  kVSRc<<<N / 8, 256, 0, stream>>>(P, W_ad + (size_t)2 * DQ * DQ,
                                   w_att + 4 * DQ, W_av + (size_t)2 * DQ * DQ,
                                   b_av + 2 * DQ, W_dec, Vc);
  kGemmR<1, PST1><<<dim3(NIT / 2, KB), 256, 0, stream>>>(Ef, Vc, P3);

  kOut<<<N / 256, 256, 0, stream>>>(P3, b_dec, mask, out);
}

// Round 14
// 210.153 us; speedup vs baseline: 1.1359x; 1.0271x over previous
//
#include <hip/hip_runtime.h>
#include <math.h>

#define N 4096
#define DQ 128
#define DIN 64
#define DC 32
#define NT 9          // full B panel: 9 n-tiles (128 v cols + z tile)
#define PST9 144
#define PST1 16
#define NIT 256       // N/16 i-tiles
#define KB 4          // grid k-splits
#define SW 8          // k-steps per wave: N / KB / 32 rows / 4 waves
#define ELS 260       // kExp LDS row stride (mod4==0 for b128, odd/32 grp -> ok)

typedef __attribute__((ext_vector_type(8))) short short8;
typedef __attribute__((ext_vector_type(8))) _Float16 half8;
typedef __attribute__((ext_vector_type(4))) float f32x4;

__device__ __forceinline__ unsigned short f2h(float x) {
  return __builtin_bit_cast(unsigned short, (_Float16)x);
}
__device__ __forceinline__ void async16(unsigned short* lds, const unsigned short* g) {
  __builtin_amdgcn_global_load_lds(
      (const __attribute__((address_space(1))) void*)g,
      (__attribute__((address_space(3))) void*)lds, 16, 0, 0);
}

// ---- kExp: Ef = f16(exp(trans)) in MFMA A-frag layout -----------------------
// One 32x256 panel per block; 8 outstanding float4 loads/thread; ONE barrier;
// per-wave transpose of 4 i-tiles (LDS stride 260: writes conflict-free,
// reads 4-way alias = 1.58x — VALU/HBM dominate anyway).
__global__ __launch_bounds__(256) void kExp(const float* __restrict__ trans,
                                            unsigned short* __restrict__ Ef) {
  __shared__ float sh[32 * ELS];
  const int tid = threadIdx.x;
  const int ip = blockIdx.x;        // i-panel of 256 (0..15)
  const int kt = blockIdx.y;        // k-tile of 32 (0..127)
  float4 v[8];
#pragma unroll
  for (int p = 0; p < 8; ++p) {
    const int f = p * 256 + tid;
    const int r = f >> 6, c = (f & 63) << 2;
    v[p] = *(const float4*)&trans[((size_t)kt * 32 + r) * N + ip * 256 + c];
  }
#pragma unroll
  for (int p = 0; p < 8; ++p) {
    const int f = p * 256 + tid;
    const int r = f >> 6, c = (f & 63) << 2;
    float4 e;
    e.x = __expf(v[p].x); e.y = __expf(v[p].y);
    e.z = __expf(v[p].z); e.w = __expf(v[p].w);
    *(float4*)&sh[r * ELS + c] = e;
  }
  __syncthreads();
  const int w = tid >> 6, lane = tid & 63;
  const int quad = lane >> 4, l15 = lane & 15;
#pragma unroll
  for (int s = 0; s < 4; ++s) {
    const int col = 64 * w + s * 16 + l15;
    unsigned short hb[8];
#pragma unroll
    for (int jj = 0; jj < 8; ++jj)
      hb[jj] = f2h(sh[(quad * 8 + jj) * ELS + col]);
    const short8 sv = {(short)hb[0], (short)hb[1], (short)hb[2], (short)hb[3],
                       (short)hb[4], (short)hb[5], (short)hb[6], (short)hb[7]};
    const int it = ip * 16 + 4 * w + s;
    *(short8*)(Ef + (((size_t)kt * NIT + it) * 64 + lane) * 8) = sv;
  }
}

// ---- shared epilogue: p*(h@W_av+b_av) -> single f16 into LDS tile -----------
__device__ __forceinline__ void v_phase(const float* hs_row, float p,
    const float* __restrict__ W_av_k, const float* __restrict__ b_av_k,
    int r, int d4, unsigned short* shh) {
  float a[4] = {b_av_k[d4], b_av_k[d4 + 1], b_av_k[d4 + 2], b_av_k[d4 + 3]};
  for (int c = 0; c < DQ; ++c) {
    const float hv = hs_row[c];
    const float4 w = *(const float4*)&W_av_k[c * DQ + d4];
    a[0] += hv * w.x; a[1] += hv * w.y; a[2] += hv * w.z; a[3] += hv * w.w;
  }
  const int nt = d4 >> 4;
#pragma unroll
  for (int e = 0; e < 4; ++e)
    shh[nt * 128 + ((d4 + e) & 15) * 8 + r] = f2h(p * a[e]);
  const int c32 = d4 >> 2;
  if (c32 < 16)
    shh[8 * 128 + c32 * 8 + r] = (c32 == 0) ? f2h(p) : 0;
}

__device__ __forceinline__ void v_store(int tid, int blk,
    const unsigned short* shh, unsigned short* __restrict__ Vf) {
  const int kt = blk >> 2, quad = blk & 3;
  if (tid < NT * 16) {
    const int nt = tid >> 4, l15 = tid & 15;
    const size_t dst = (((size_t)kt * NT + nt) * 64 + quad * 16 + l15) * 8;
    *(short8*)(Vf + dst) = *(const short8*)&shh[nt * 128 + l15 * 8];
  }
}

// ---- round 0: encode + sa + p + V' fused (8 rows per block) ----
__global__ __launch_bounds__(256) void kVS0(const float* __restrict__ x,
    const float* __restrict__ comms, const float* __restrict__ W_enc,
    const float* __restrict__ b_enc, const float* __restrict__ W_ad_k,
    const float* __restrict__ wa, const float* __restrict__ W_av_k,
    const float* __restrict__ b_av_k, unsigned short* __restrict__ Vf) {
  __shared__ float xs[8][96];
  __shared__ float hs[8][DQ];
  __shared__ float u[DQ];
  __shared__ float pb[8];
  __shared__ __align__(16) unsigned short shh[NT * 128];
  const int tid = threadIdx.x;
  const int blk = blockIdx.x;
  if (tid < 128) {
    const float4 v = *(const float4*)&x[(size_t)blk * 8 * DIN + tid * 4];
    const int idx = tid * 4, r = idx >> 6, c = idx & 63;
    xs[r][c] = v.x; xs[r][c + 1] = v.y; xs[r][c + 2] = v.z; xs[r][c + 3] = v.w;
  } else if (tid < 192) {
    const int t = tid - 128;
    const float4 v = *(const float4*)&comms[(size_t)blk * 8 * DC + t * 4];
    const int idx = t * 4, r = idx >> 5, c = idx & 31;
    xs[r][64 + c] = v.x; xs[r][64 + c + 1] = v.y; xs[r][64 + c + 2] = v.z; xs[r][64 + c + 3] = v.w;
  }
  if (tid < DQ) {
    float s = 0.f;
    const float* wrow = &W_ad_k[tid * DQ];
    for (int q = 0; q < DQ; ++q) s += wrow[q] * wa[q];
    u[tid] = s;
  }
  __syncthreads();
  const int r = tid >> 5;
  const int c32 = tid & 31;
  const int d4 = c32 * 4;
  {
    float a0 = b_enc[d4], a1 = b_enc[d4 + 1], a2 = b_enc[d4 + 2], a3 = b_enc[d4 + 3];
    for (int c = 0; c < 96; ++c) {
      const float hv = xs[r][c];
      const float4 w = *(const float4*)&W_enc[c * DQ + d4];
      a0 += hv * w.x; a1 += hv * w.y; a2 += hv * w.z; a3 += hv * w.w;
    }
    hs[r][d4] = a0; hs[r][d4 + 1] = a1; hs[r][d4 + 2] = a2; hs[r][d4 + 3] = a3;
  }
  __syncthreads();
  float part = 0.f;
  for (int c = c32; c < DQ; c += 32) part += hs[r][c] * u[c];
#pragma unroll
  for (int m = 16; m > 0; m >>= 1) part += __shfl_xor(part, m, 32);
  if (c32 == 0) pb[r] = __expf(part);
  __syncthreads();
  v_phase(hs[r], pb[r], W_av_k, b_av_k, r, d4, shh);
  __syncthreads();
  v_store(tid, blk, shh, Vf);
}

// ---- round 1: P-reduce -> h + sa + p + V' (full panel) ----
__global__ __launch_bounds__(256) void kVSR(const float* __restrict__ P,
    const float* __restrict__ W_ad_k, const float* __restrict__ wa,
    const float* __restrict__ W_av_k, const float* __restrict__ b_av_k,
    unsigned short* __restrict__ Vf) {
  __shared__ float hs[8][DQ];
  __shared__ float u[DQ];
  __shared__ float pb[8];
  __shared__ __align__(16) unsigned short shh[NT * 128];
  const int tid = threadIdx.x;
  const int r = tid >> 5;
  const int c32 = tid & 31;
  const int d4 = c32 * 4;
  const int j = blockIdx.x * 8 + r;
  if (tid < DQ) {
    float s = 0.f;
    const float* wrow = &W_ad_k[tid * DQ];
    for (int q = 0; q < DQ; ++q) s += wrow[q] * wa[q];
    u[tid] = s;
  }
  float4 num = {0.f, 0.f, 0.f, 0.f};
  float den = 0.f;
#pragma unroll
  for (int s = 0; s < KB; ++s) {
    const float* b = &P[((size_t)s * N + j) * PST9];
    const float4 v = *(const float4*)&b[d4];
    num.x += v.x; num.y += v.y; num.z += v.z; num.w += v.w;
    den += b[128];
  }
  const float inv = 1.f / den;
  hs[r][d4] = num.x * inv; hs[r][d4 + 1] = num.y * inv;
  hs[r][d4 + 2] = num.z * inv; hs[r][d4 + 3] = num.w * inv;
  __syncthreads();
  float part = 0.f;
  for (int c = c32; c < DQ; c += 32) part += hs[r][c] * u[c];
#pragma unroll
  for (int m = 16; m > 0; m >>= 1) part += __shfl_xor(part, m, 32);
  if (c32 == 0) pb[r] = __expf(part);
  __syncthreads();
  v_phase(hs[r], pb[r], W_av_k, b_av_k, r, d4, shh);
  __syncthreads();
  v_store(tid, blockIdx.x, shh, Vf);
}

// ---- round 2: P-reduce -> h + sa + p + CONTRACTED V' (v.W_dec, p) ----
__global__ __launch_bounds__(256) void kVSRc(const float* __restrict__ P,
    const float* __restrict__ W_ad_k, const float* __restrict__ wa,
    const float* __restrict__ W_av_k, const float* __restrict__ b_av_k,
    const float* __restrict__ W_dec, unsigned short* __restrict__ Vc) {
  __shared__ float hs[8][DQ];
  __shared__ float u[DQ];
  __shared__ float pb[8];
  const int tid = threadIdx.x;
  const int r = tid >> 5;
  const int c32 = tid & 31;
  const int d4 = c32 * 4;
  const int j = blockIdx.x * 8 + r;
  if (tid < DQ) {
    float s = 0.f;
    const float* wrow = &W_ad_k[tid * DQ];
    for (int q = 0; q < DQ; ++q) s += wrow[q] * wa[q];
    u[tid] = s;
  }
  float4 num = {0.f, 0.f, 0.f, 0.f};
  float den = 0.f;
#pragma unroll
  for (int s = 0; s < KB; ++s) {
    const float* b = &P[((size_t)s * N + j) * PST9];
    const float4 v = *(const float4*)&b[d4];
    num.x += v.x; num.y += v.y; num.z += v.z; num.w += v.w;
    den += b[128];
  }
  const float inv = 1.f / den;
  hs[r][d4] = num.x * inv; hs[r][d4 + 1] = num.y * inv;
  hs[r][d4 + 2] = num.z * inv; hs[r][d4 + 3] = num.w * inv;
  __syncthreads();
  float part = 0.f;
  for (int c = c32; c < DQ; c += 32) part += hs[r][c] * u[c];
#pragma unroll
  for (int m = 16; m > 0; m >>= 1) part += __shfl_xor(part, m, 32);
  if (c32 == 0) pb[r] = __expf(part);
  __syncthreads();
  float a[4] = {b_av_k[d4], b_av_k[d4 + 1], b_av_k[d4 + 2], b_av_k[d4 + 3]};
  for (int c = 0; c < DQ; ++c) {
    const float hv = hs[r][c];
    const float4 w = *(const float4*)&W_av_k[c * DQ + d4];
    a[0] += hv * w.x; a[1] += hv * w.y; a[2] += hv * w.z; a[3] += hv * w.w;
  }
  float vd = a[0] * W_dec[d4] + a[1] * W_dec[d4 + 1]
           + a[2] * W_dec[d4 + 2] + a[3] * W_dec[d4 + 3];
#pragma unroll
  for (int m = 16; m > 0; m >>= 1) vd += __shfl_xor(vd, m, 32);
  const float p = pb[r];
  if (c32 < 16) {
    const int blk = blockIdx.x;
    const size_t ix = (((size_t)(blk >> 2)) * 64 + (blk & 3) * 16 + c32) * 8 + r;
    Vc[ix] = (c32 == 0) ? f2h(p * vd) : (c32 == 1) ? f2h(p) : 0;
  }
}

// ---- MFMA GEMM, in-block k-split (R11 structure, measured good) -------------
template <int NTT, int PST>
__global__ __launch_bounds__(256) void kGemmR(
    const unsigned short* __restrict__ Ef, const unsigned short* __restrict__ Vf,
    float* __restrict__ P) {
  __shared__ __align__(16) unsigned short lds[4 * 2 * NTT * 512];
  const int tid = threadIdx.x;
  const int w = tid >> 6, lane = tid & 63;
  const int quad = lane >> 4, l15 = lane & 15;
  const int it0 = blockIdx.x * 2;
  const size_t ktw = (size_t)blockIdx.y * (4 * SW) + w * SW;
  unsigned short* myL = lds + w * (2 * NTT * 512);

  f32x4 acc[2][NTT];
#pragma unroll
  for (int ti = 0; ti < 2; ++ti)
#pragma unroll
    for (int nt = 0; nt < NTT; ++nt) acc[ti][nt] = (f32x4){0.f, 0.f, 0.f, 0.f};

#pragma unroll
  for (int c = 0; c < NTT; ++c)
    async16(myL + c * 512, Vf + (ktw * NTT + c) * 512 + lane * 8);
  half8 A0[2], A1[2];
#pragma unroll
  for (int ti = 0; ti < 2; ++ti)
    A0[ti] = __builtin_bit_cast(half8,
        *(const short8*)(Ef + ((ktw * NIT + it0 + ti) * 64 + lane) * 8));

#pragma unroll
  for (int t = 0; t < SW; ++t) {
    if (t + 1 < SW) {
      const size_t ktn = ktw + t + 1;
#pragma unroll
      for (int c = 0; c < NTT; ++c)
        async16(myL + ((t + 1) & 1) * NTT * 512 + c * 512,
                Vf + (ktn * NTT + c) * 512 + lane * 8);
#pragma unroll
      for (int ti = 0; ti < 2; ++ti)
        A1[ti] = __builtin_bit_cast(half8,
            *(const short8*)(Ef + ((ktn * NIT + it0 + ti) * 64 + lane) * 8));
      __builtin_amdgcn_s_waitcnt(0xF70 | (NTT + 2));
    } else {
      __builtin_amdgcn_s_waitcnt(0xF70);
    }
    const unsigned short* bb = myL + (t & 1) * NTT * 512;
#pragma unroll
    for (int nt = 0; nt < NTT; ++nt) {
      const half8 Bh = __builtin_bit_cast(half8,
          *(const short8*)(bb + nt * 512 + lane * 8));
      acc[0][nt] = __builtin_amdgcn_mfma_f32_16x16x32_f16(A0[0], Bh, acc[0][nt], 0, 0, 0);
      acc[1][nt] = __builtin_amdgcn_mfma_f32_16x16x32_f16(A0[1], Bh, acc[1][nt], 0, 0, 0);
    }
    if (t + 1 < SW) { A0[0] = A1[0]; A0[1] = A1[1]; }
  }
  __syncthreads();
  float* lf = (float*)lds;
#pragma unroll
  for (int ti = 0; ti < 2; ++ti)
#pragma unroll
    for (int nt = 0; nt < NTT; ++nt) {
      float4 v; v.x = acc[ti][nt][0]; v.y = acc[ti][nt][1];
      v.z = acc[ti][nt][2]; v.w = acc[ti][nt][3];
      *(float4*)&lf[(w * 2 * NTT + ti * NTT + nt) * 256 + lane * 4] = v;
    }
  __syncthreads();
  float* Pb = P + (size_t)blockIdx.y * N * PST;
  for (int p = w; p < 2 * NTT; p += 4) {
    const int ti = p / NTT, nt = p % NTT;
    float4 s = {0.f, 0.f, 0.f, 0.f};
#pragma unroll
    for (int wv = 0; wv < 4; ++wv) {
      const float4 v = *(const float4*)&lf[(wv * 2 * NTT + p) * 256 + lane * 4];
      s.x += v.x; s.y += v.y; s.z += v.z; s.w += v.w;
    }
    const float sr[4] = {s.x, s.y, s.z, s.w};
    if (NTT == 1 || nt != 8 || l15 == 0) {
#pragma unroll
      for (int r = 0; r < 4; ++r) {
        const int i = (it0 + ti) * 16 + quad * 4 + r;
        Pb[(size_t)i * PST + nt * 16 + l15] = sr[r];
      }
    }
  }
}

// ---- final: out[i] = numc/den + b_dec (P3 has 2 live cols) ----
__global__ __launch_bounds__(256) void kOut(const float* __restrict__ P3,
    const float* __restrict__ b_dec, const int* __restrict__ mask,
    float* __restrict__ out) {
  const int i = blockIdx.x * 256 + threadIdx.x;
  float num = 0.f, den = 0.f;
#pragma unroll
  for (int s = 0; s < KB; ++s) {
    const float* b = &P3[((size_t)s * N + i) * PST1];
    num += b[0];
    den += b[1];
  }
  out[i] = (mask[i] == 0) ? -INFINITY : num / den + b_dec[0];
}

extern "C" void kernel_launch(void* const* d_in, const int* in_sizes, int n_in,
                              void* d_out, int out_size, void* d_ws, size_t ws_size,
                              hipStream_t stream) {
  (void)in_sizes; (void)n_in; (void)out_size; (void)ws_size;
  const float* x     = (const float*)d_in[0];
  const float* comms = (const float*)d_in[1];
  const float* trans = (const float*)d_in[2];
  const int*   mask  = (const int*)d_in[3];
  const float* W_enc = (const float*)d_in[4];
  const float* b_enc = (const float*)d_in[5];
  const float* W_ad  = (const float*)d_in[6];
  // d_in[7]=b_ad, d_in[9]=b_att cancel inside the row softmax
  const float* w_att = (const float*)d_in[8];
  const float* W_av  = (const float*)d_in[10];
  const float* b_av  = (const float*)d_in[11];
  const float* W_dec = (const float*)d_in[12];
  const float* b_dec = (const float*)d_in[13];
  float* out         = (float*)d_out;

  char* ws = (char*)d_ws;
  unsigned short* Vf = (unsigned short*)ws;  ws += (size_t)(N / 32) * NT * 512 * 2;
  unsigned short* Vc = (unsigned short*)ws;  ws += (size_t)(N / 32) * 512 * 2;
  unsigned short* Ef = (unsigned short*)ws;  ws += (size_t)N * N * 2;
  float* P  = (float*)ws;                    ws += (size_t)KB * N * PST9 * 4;
  float* P3 = (float*)ws;

  kExp<<<dim3(16, 128), 256, 0, stream>>>(trans, Ef);
  kVS0<<<N / 8, 256, 0, stream>>>(x, comms, W_enc, b_enc, W_ad, w_att,
                                  W_av, b_av, Vf);
  kGemmR<NT, PST9><<<dim3(NIT / 2, KB), 256, 0, stream>>>(Ef, Vf, P);

  kVSR<<<N / 8, 256, 0, stream>>>(P, W_ad + (size_t)1 * DQ * DQ,
                                  w_att + 2 * DQ, W_av + (size_t)1 * DQ * DQ,
                                  b_av + DQ, Vf);
  kGemmR<NT, PST9><<<dim3(NIT / 2, KB), 256, 0, stream>>>(Ef, Vf, P);

  kVSRc<<<N / 8, 256, 0, stream>>>(P, W_ad + (size_t)2 * DQ * DQ,
                                   w_att + 4 * DQ, W_av + (size_t)2 * DQ * DQ,
                                   b_av + 2 * DQ, W_dec, Vc);
  kGemmR<1, PST1><<<dim3(NIT / 2, KB), 256, 0, stream>>>(Ef, Vc, P3);

  kOut<<<N / 256, 256, 0, stream>>>(P3, b_dec, mask, out);
}